// Round 1
// baseline (119.506 us; speedup 1.0000x reference)
//
#include <hip/hip_runtime.h>

namespace {

constexpr int T_LEN = 262144;   // samples per batch
constexpr int NF    = 1024;     // frames per batch
constexpr int P     = 22;       // LPC order
constexpr int JPW   = 16;       // output blocks (256-sample) per workgroup
constexpr int GPB   = 65;       // groups per batch: ceil(1025/16)
constexpr int WARM  = 256;      // warmup samples before each chunk
constexpr float TWO_PI = 6.283185307179586f;

// One wave (64 threads) per workgroup.
// Producer view : lane = k*16 + jl.  jl in [0,16): local output block, k in [0,4): overlap slot.
//   frame f = (j0+jl) - k, chunk covers frame-local samples [k*256, k*256+256),
//   warm-started (zero state) at k*256 - WARM (exact for k<=1, err ~1e-5 for k=2,3).
// Reducer view  : lane = jlr*4 + (lane&3); each lane combines 4 overlap slots for 8 samples.
__global__ __launch_bounds__(64)
void lpc_ola_kernel(const float* __restrict__ ex,
                    const float* __restrict__ gain,
                    const float* __restrict__ a,
                    float* __restrict__ out)
{
    __shared__ float wtab[1024];     // hann window, 4 KB
    __shared__ float red[32 * 64];   // [r_local][jl*4 + k], 8 KB staging

    const int lane = threadIdx.x;
    const int b    = blockIdx.x / GPB;
    const int g    = blockIdx.x % GPB;
    const int j0   = 1 + g * JPW;    // first padded 256-block this wave owns

    // Build hann table: w[m] = 0.5*(1 - cos(2*pi*m/1024))
    #pragma unroll
    for (int i = 0; i < 16; ++i) {
        int m = lane * 16 + i;
        wtab[m] = 0.5f * (1.0f - __cosf(TWO_PI * (float)m * (1.0f / 1024.0f)));
    }
    __syncthreads();

    const int k  = lane >> 4;
    const int jl = lane & 15;
    const int j  = j0 + jl;
    const int f  = j - k;
    const bool fv = (unsigned)f < (unsigned)NF;
    const int  fc = fv ? f : 0;
    const float gv = fv ? gain[b * NF + fc] : 0.0f;   // gv=0 keeps invalid lanes at y=0

    float ma[P], s[P];
    #pragma unroll
    for (int p = 0; p < P; ++p) {
        ma[p] = -a[(b * NF + fc) * P + p];
        s[p]  = 0.0f;
    }

    const float* exb  = ex  + b * T_LEN;
    float*       outb = out + b * T_LEN;

    // ex index at step 0: f*256 + (k*256 - WARM) - 384 = j*256 - WARM - 384 (k-independent)
    int xi = j * 256 - WARM - 384;
    const int ldsbase = jl * 4 + k;

    // ---- warmup: WARM steps, outputs discarded ----
    #pragma unroll 1
    for (int it = 0; it < WARM / 4; ++it) {
        float4 x4 = make_float4(0.f, 0.f, 0.f, 0.f);
        if ((unsigned)xi < (unsigned)T_LEN) x4 = *(const float4*)(exb + xi);
        xi += 4;
        float xv[4] = {x4.x, x4.y, x4.z, x4.w};
        #pragma unroll
        for (int u = 0; u < 4; ++u) {
            float y = fmaf(gv, xv[u], s[0]);
            #pragma unroll
            for (int p = 0; p < P - 1; ++p) s[p] = fmaf(ma[p], y, s[p + 1]);
            s[P - 1] = ma[P - 1] * y;
        }
    }

    const int jlr = lane >> 2;
    const int jr  = j0 + jlr;
    const int l3  = lane & 3;

    // ---- output: 8 subchunks of 32 samples ----
    #pragma unroll 1
    for (int sc = 0; sc < 8; ++sc) {
        #pragma unroll 1
        for (int it = 0; it < 8; ++it) {
            float4 x4 = make_float4(0.f, 0.f, 0.f, 0.f);
            if ((unsigned)xi < (unsigned)T_LEN) x4 = *(const float4*)(exb + xi);
            xi += 4;
            float xv[4] = {x4.x, x4.y, x4.z, x4.w};
            #pragma unroll
            for (int u = 0; u < 4; ++u) {
                float y = fmaf(gv, xv[u], s[0]);
                #pragma unroll
                for (int p = 0; p < P - 1; ++p) s[p] = fmaf(ma[p], y, s[p + 1]);
                s[P - 1] = ma[P - 1] * y;
                red[(it * 4 + u) * 64 + ldsbase] = y;   // raw (unwindowed) y
            }
        }
        __syncthreads();

        // Reduce 4 overlap slots -> 8 output samples per lane (two contiguous float4s)
        #pragma unroll
        for (int h = 0; h < 2; ++h) {
            float o[4];
            #pragma unroll
            for (int i = 0; i < 4; ++i) {
                int r = l3 * 4 + h * 16 + i;            // subchunk-local sample
                const float4 y4 = *(const float4*)&red[r * 64 + jlr * 4];
                const float yk[4] = {y4.x, y4.y, y4.z, y4.w};
                float acc = 0.0f, wsum = 0.0f;
                #pragma unroll
                for (int kk = 0; kk < 4; ++kk) {
                    float wv = ((unsigned)(jr - kk) < (unsigned)NF)
                                   ? wtab[kk * 256 + sc * 32 + r] : 0.0f;
                    acc   = fmaf(wv, yk[kk], acc);
                    wsum += wv;
                }
                o[i] = acc / wsum;   // wsum==2 in interior; edge-correct via masks
            }
            int tb = jr * 256 + sc * 32 + l3 * 4 + h * 16 - 384;  // 4-aligned
            if ((unsigned)tb < (unsigned)T_LEN) {
                *(float4*)(outb + tb) = make_float4(o[0], o[1], o[2], o[3]);
            }
        }
        __syncthreads();
    }
}

} // namespace

extern "C" void kernel_launch(void* const* d_in, const int* in_sizes, int n_in,
                              void* d_out, int out_size, void* d_ws, size_t ws_size,
                              hipStream_t stream)
{
    (void)in_sizes; (void)n_in; (void)out_size; (void)d_ws; (void)ws_size;
    const float* ex   = (const float*)d_in[0];
    const float* gain = (const float*)d_in[1];
    const float* a    = (const float*)d_in[2];
    float* out        = (float*)d_out;

    dim3 grid(16 * GPB);   // 1040 single-wave workgroups (~4 per CU)
    dim3 block(64);
    hipLaunchKernelGGL(lpc_ola_kernel, grid, block, 0, stream, ex, gain, a, out);
}

// Round 2
// 94.250 us; speedup vs baseline: 1.2680x; 1.2680x over previous
//
#include <hip/hip_runtime.h>

namespace {

typedef float v2f __attribute__((ext_vector_type(2)));

constexpr int T_LEN = 262144;   // samples per batch
constexpr int NF    = 1024;     // frames per batch
constexpr int P     = 22;       // LPC order
constexpr float TWO_PI = 6.283185307179586f;

// Single-wave workgroup: LDS ops from one wave complete in order -> no s_barrier
// needed, only a compiler reordering fence (avoids the vmcnt(0) drain).
#define LDS_FENCE() asm volatile("" ::: "memory")

__device__ __forceinline__ void ld8(const float* __restrict__ exb, int xi,
                                    float4 (&buf)[8]) {
    #pragma unroll
    for (int q = 0; q < 8; ++q) {
        int idx = xi + q * 4;
        float4 v = make_float4(0.f, 0.f, 0.f, 0.f);
        if ((unsigned)idx < (unsigned)T_LEN) v = *(const float4*)(exb + idx);
        buf[q] = v;
    }
}

// 32 samples of order-22 IIR (transposed DF-II), state packed as
// sv[j] = (s[j], s[j+11]) so the shift maps onto packed fma:
//   s'[j]    = ma[j]*y    + s[j+1]      (lo half, c = sv[j+1].lo)
//   s'[j+11] = ma[j+11]*y + s[j+12]     (hi half, c = sv[j+1].hi)
// tails: s'[10] = ma[10]*y + old s[11]; s'[21] = ma[21]*y.
template <bool STORE>
__device__ __forceinline__ void proc32(const float4 (&buf)[8], v2f (&sv)[11],
                                       const v2f (&mav)[11], float gv,
                                       float* red, int ldsbase) {
    #pragma unroll
    for (int q = 0; q < 8; ++q) {
        const float xv[4] = {buf[q].x, buf[q].y, buf[q].z, buf[q].w};
        #pragma unroll
        for (int u = 0; u < 4; ++u) {
            float y   = fmaf(gv, xv[u], sv[0].x);
            float s11 = sv[0].y;
            v2f yy = (v2f){y, y};
            #pragma unroll
            for (int j = 0; j < 10; ++j)
                sv[j] = __builtin_elementwise_fma(mav[j], yy, sv[j + 1]);
            sv[10].x = fmaf(mav[10].x, y, s11);
            sv[10].y = mav[10].y * y;
            if (STORE) red[(q * 4 + u) * 64 + ldsbase] = y;
        }
    }
}

__global__ __launch_bounds__(64)
void lpc_ola_kernel(const float* __restrict__ ex,
                    const float* __restrict__ gain,
                    const float* __restrict__ a,
                    float* __restrict__ out)
{
    __shared__ __align__(16) float wtab[1024];   // hann window
    __shared__ __align__(16) float red[32 * 64]; // y staging [row][task*4+k]

    const int lane = threadIdx.x;
    const int w    = blockIdx.x;

    #pragma unroll
    for (int i = 0; i < 16; ++i) {
        int mm = lane * 16 + i;
        wtab[mm] = 0.5f * (1.0f - __cosf(TWO_PI * (float)mm * (1.0f / 1024.0f)));
    }
    LDS_FENCE();

    // ---- producer mapping: lane = k*16 + jl, task tau = w*16 + jl ----
    // m in [0,1023): regular block jr = m+2 (covers jr 2..1024).
    // m == 1023   : merged edge task, lanes k<2 -> jr=1, k>=2 -> jr=1025.
    const int k   = lane >> 4;
    const int jl  = lane & 15;
    const int tau = w * 16 + jl;
    const int b   = tau >> 10;
    const int m   = tau & 1023;
    const bool mrg = (m == 1023);
    const int jr  = mrg ? ((k < 2) ? 1 : 1025) : (m + 2);
    const int f   = jr - k;
    const bool fv = (unsigned)f < (unsigned)NF;
    const int fc  = fv ? f : 0;
    const float gv = fv ? gain[b * NF + fc] : 0.0f;  // gv=0 keeps invalid lanes at y=0

    float ma[P];
    #pragma unroll
    for (int p = 0; p < P; ++p) ma[p] = -a[(b * NF + fc) * P + p];
    v2f mav[11];
    #pragma unroll
    for (int j = 0; j < 11; ++j) mav[j] = (v2f){ma[j], ma[j + 11]};

    v2f sv[11];
    #pragma unroll
    for (int j = 0; j < 11; ++j) sv[j] = (v2f){0.f, 0.f};

    const float* exb = ex + (size_t)b * T_LEN;
    const int ldsbase = jl * 4 + k;
    // out-coord of first warmup sample: jr*256 - 384 - 256 (k-independent)
    int xi = jr * 256 - 640;

    // ---- reducer mapping: lane = jlr*4 + l3 ----
    const int jlr  = lane >> 2;
    const int l3   = lane & 3;
    const int taur = w * 16 + jlr;
    const int br   = taur >> 10;
    const int mr   = taur & 1023;
    const bool mrgr = (mr == 1023);
    float* outbr = out + (size_t)br * T_LEN;

    float4 bufA[8], bufB[8];

    // ---- warmup: 8 blocks of 32 samples, double-buffered prefetch ----
    ld8(exb, xi, bufA); xi += 32;
    #pragma unroll 1
    for (int it = 0; it < 4; ++it) {
        ld8(exb, xi, bufB); xi += 32;
        proc32<false>(bufA, sv, mav, gv, red, ldsbase);
        ld8(exb, xi, bufA); xi += 32;
        proc32<false>(bufB, sv, mav, gv, red, ldsbase);
    }

    // ---- output: 8 blocks of 32 samples (one per sc), produce + reduce ----
    #pragma unroll 1
    for (int sc = 0; sc < 8; sc += 2) {
        #pragma unroll
        for (int half = 0; half < 2; ++half) {
            const int scc = sc + half;
            if (half == 0) { ld8(exb, xi, bufB); xi += 32;
                             proc32<true>(bufA, sv, mav, gv, red, ldsbase); }
            else           { ld8(exb, xi, bufA); xi += 32;
                             proc32<true>(bufB, sv, mav, gv, red, ldsbase); }
            LDS_FENCE();
            // reduce: each lane combines 4 overlap slots for 8 samples
            #pragma unroll
            for (int h = 0; h < 2; ++h) {
                const int r0  = l3 * 4 + h * 16;   // 0..28, block-local /4
                const int rg0 = scc * 32 + r0;     // 0..252, block sample
                const bool hi = rg0 >= 128;
                float o[4];
                #pragma unroll
                for (int i = 0; i < 4; ++i) {
                    const int r  = r0 + i;
                    const int rg = rg0 + i;
                    const float4 y4 = *(const float4*)&red[r * 64 + jlr * 4];
                    const float yk[4] = {y4.x, y4.y, y4.z, y4.w};
                    float acc = 0.f, wsum = 0.f;
                    #pragma unroll
                    for (int kk = 0; kk < 4; ++kk) {
                        bool val = mrgr ? (hi ? (kk < 2) : (kk >= 2))
                                        : ((unsigned)(mr + 2 - kk) < (unsigned)NF);
                        float wv = val ? wtab[kk * 256 + rg] : 0.f;
                        acc   = fmaf(wv, yk[kk], acc);
                        wsum += wv;
                    }
                    o[i] = acc * __builtin_amdgcn_rcpf(wsum);
                }
                // regular: tb = (mr+2)*256 - 384 + rg, always in [128, 262016)
                // merged : upper half -> [0,128), lower half -> [262016, 262144)
                int tb = (mrgr ? (hi ? -128 : 262016) : (mr * 256 + 128)) + rg0;
                *(float4*)(outbr + tb) = make_float4(o[0], o[1], o[2], o[3]);
            }
            LDS_FENCE();
        }
    }
}

} // namespace

extern "C" void kernel_launch(void* const* d_in, const int* in_sizes, int n_in,
                              void* d_out, int out_size, void* d_ws, size_t ws_size,
                              hipStream_t stream)
{
    (void)in_sizes; (void)n_in; (void)out_size; (void)d_ws; (void)ws_size;
    const float* ex   = (const float*)d_in[0];
    const float* gain = (const float*)d_in[1];
    const float* a    = (const float*)d_in[2];
    float* out        = (float*)d_out;

    dim3 grid(1024);   // 16 batches x 1024 tasks / 16 tasks per wave -> exactly 4 blocks/CU
    dim3 block(64);
    hipLaunchKernelGGL(lpc_ola_kernel, grid, block, 0, stream, ex, gain, a, out);
}

// Round 3
// 91.200 us; speedup vs baseline: 1.3104x; 1.0334x over previous
//
#include <hip/hip_runtime.h>

namespace {

typedef float v2f __attribute__((ext_vector_type(2)));

constexpr int T_LEN = 262144;   // samples per batch
constexpr int NF    = 1024;     // frames per batch
constexpr int P     = 22;       // LPC order

// Single-wave workgroup: LDS ops from one wave complete in order -> no s_barrier,
// only a compiler reordering fence (avoids vmcnt(0)/lgkmcnt(0) drains).
#define LDS_FENCE() asm volatile("" ::: "memory")

template <bool CK>
__device__ __forceinline__ void ld8(const float* __restrict__ exb, int xi,
                                    float4 (&buf)[8]) {
    #pragma unroll
    for (int q = 0; q < 8; ++q) {
        int idx = xi + q * 4;
        if (CK) {
            float4 v = make_float4(0.f, 0.f, 0.f, 0.f);
            if ((unsigned)idx < (unsigned)T_LEN) v = *(const float4*)(exb + idx);
            buf[q] = v;
        } else {
            buf[q] = *(const float4*)(exb + idx);   // proven in-bounds
        }
    }
}

// 32 samples of order-22 IIR (transposed DF-II), state packed (s[j], s[j+11])
// so the delay-line shift maps onto v_pk_fma_f32.
template <bool STORE>
__device__ __forceinline__ void proc32(const float4 (&buf)[8], v2f (&sv)[11],
                                       const v2f (&mav)[11], float gv,
                                       float* red, int ldsbase) {
    #pragma unroll
    for (int q = 0; q < 8; ++q) {
        const float xv[4] = {buf[q].x, buf[q].y, buf[q].z, buf[q].w};
        #pragma unroll
        for (int u = 0; u < 4; ++u) {
            float y   = fmaf(gv, xv[u], sv[0].x);
            float s11 = sv[0].y;
            v2f yy = (v2f){y, y};
            #pragma unroll
            for (int j = 0; j < 10; ++j)
                sv[j] = __builtin_elementwise_fma(mav[j], yy, sv[j + 1]);
            sv[10].x = fmaf(mav[10].x, y, s11);
            sv[10].y = mav[10].y * y;
            if (STORE) red[(q * 4 + u) * 64 + ldsbase] = y;
        }
    }
}

// Tasks: per batch, 2048 output blocks of 128 samples (i = 3..2050, padded base
// i*128, out base i*128-384). Block i gets 4 overlap slots kk=0..3 from frames
// f = (i>>1) - kk, frame-local start m0 = i*128 - f*256. Warm = 128 samples.
__global__ __launch_bounds__(64, 2)
void lpc_ola_kernel(const float* __restrict__ ex,
                    const float* __restrict__ gain,
                    const float* __restrict__ a,
                    float* __restrict__ out)
{
    __shared__ __align__(16) float red[32 * 64];  // y staging [row][task*4+kk]

    const int lane = threadIdx.x;
    const int w    = blockIdx.x;
    const int wloc = w & 127;                 // wave-in-batch (128 waves/batch)
    const bool chk  = (wloc == 0);            // warm loads may touch idx<0
    const bool edge = (wloc == 0) | (wloc == 127);  // partial-frame wsum path

    // ---- producer mapping: lane = kk*16 + jl ----
    const int kk  = lane >> 4;
    const int jl  = lane & 15;
    const int tau = w * 16 + jl;
    const int b   = tau >> 11;
    const int i   = (tau & 2047) + 3;
    const int fi  = i >> 1;
    const int f   = fi - kk;
    const bool fv = (unsigned)f < (unsigned)NF;
    const int fc  = fv ? f : 0;
    const float gv = fv ? gain[b * NF + fc] : 0.0f;  // gv=0 zeroes invalid slots

    float man[P];
    const float2* ap = (const float2*)(a + (size_t)(b * NF + fc) * P);
    #pragma unroll
    for (int j = 0; j < 11; ++j) {
        float2 t = ap[j];
        man[2 * j]     = -t.x;
        man[2 * j + 1] = -t.y;
    }
    v2f mav[11];
    #pragma unroll
    for (int j = 0; j < 11; ++j) mav[j] = (v2f){man[j], man[j + 11]};
    v2f sv[11];
    #pragma unroll
    for (int j = 0; j < 11; ++j) sv[j] = (v2f){0.f, 0.f};

    const float* exb = ex + (size_t)b * T_LEN;
    const int ldsbase = jl * 4 + kk;
    int xi = i * 128 - 512;       // ex index of first warm sample (k-independent)

    // ---- reducer mapping: lane = jlr*4 + l3 ----
    const int jlr  = lane >> 2;
    const int l3   = lane & 3;
    const int taur = w * 16 + jlr;
    const int br   = taur >> 11;
    const int ir   = (taur & 2047) + 3;
    const int fir  = ir >> 1;
    const int m00b = (ir & 1) << 7;           // frame-local offset of slot 0
    float* outbr   = out + (size_t)br * T_LEN;
    const float mk0 = ((unsigned)(fir - 0) < (unsigned)NF) ? 1.f : 0.f;
    const float mk1 = ((unsigned)(fir - 1) < (unsigned)NF) ? 1.f : 0.f;
    const float mk2 = ((unsigned)(fir - 2) < (unsigned)NF) ? 1.f : 0.f;
    const float mk3 = ((unsigned)(fir - 3) < (unsigned)NF) ? 1.f : 0.f;

    auto reduce32 = [&](int sc) {
        const int ob = ir * 128 - 384 + sc * 32;
        #pragma unroll
        for (int h = 0; h < 2; ++h) {
            float o[4];
            #pragma unroll
            for (int ii = 0; ii < 4; ++ii) {
                const int r  = h * 16 + l3 * 4 + ii;
                const float4 y4 = *(const float4*)&red[r * 64 + jlr * 4];
                const int rg = sc * 32 + r;
                const float rev = (float)(m00b + rg) * (1.0f / 1024.0f);
                const float c = __builtin_amdgcn_cosf(rev);  // cos(2*pi*rev)
                const float s = __builtin_amdgcn_sinf(rev);
                float acc = (y4.x + y4.z) + (y4.y + y4.w);
                acc = fmaf(c, y4.z - y4.x, acc);
                acc = fmaf(s, y4.y - y4.w, acc);
                if (!edge) {
                    o[ii] = acc * 0.25f;      // interior: wsum == 2 exactly
                } else {
                    const float w0 = 0.5f * (1.f - c), w1 = 0.5f * (1.f + s);
                    const float w2 = 0.5f * (1.f + c), w3 = 0.5f * (1.f - s);
                    float wsum = mk0 * w0;
                    wsum = fmaf(mk1, w1, wsum);
                    wsum = fmaf(mk2, w2, wsum);
                    wsum = fmaf(mk3, w3, wsum);
                    o[ii] = acc * 0.5f * __builtin_amdgcn_rcpf(wsum);
                }
            }
            *(float4*)(outbr + ob + h * 16 + l3 * 4) =
                make_float4(o[0], o[1], o[2], o[3]);
        }
    };

    float4 bufA[8], bufB[8];
    auto ldW = [&](float4 (&buf)[8]) {   // warm-phase load (checked in edge wave)
        if (chk) ld8<true>(exb, xi, buf); else ld8<false>(exb, xi, buf);
        xi += 32;
    };

    // ---- warm: blocks b0..b3 (128 samples), double-buffered ----
    ldW(bufA);
    ldW(bufB); proc32<false>(bufA, sv, mav, gv, red, ldsbase);
    ldW(bufA); proc32<false>(bufB, sv, mav, gv, red, ldsbase);
    ldW(bufB); proc32<false>(bufA, sv, mav, gv, red, ldsbase);
    ld8<false>(exb, xi, bufA); xi += 32;            // b4 (out phase, in-bounds)
    proc32<false>(bufB, sv, mav, gv, red, ldsbase); // b3

    // ---- out: blocks b4..b7 (128 samples), produce -> reduce ----
    ld8<false>(exb, xi, bufB); xi += 32;            // b5
    proc32<true>(bufA, sv, mav, gv, red, ldsbase);
    LDS_FENCE(); reduce32(0); LDS_FENCE();
    ld8<false>(exb, xi, bufA); xi += 32;            // b6
    proc32<true>(bufB, sv, mav, gv, red, ldsbase);
    LDS_FENCE(); reduce32(1); LDS_FENCE();
    ld8<false>(exb, xi, bufB); xi += 32;            // b7
    proc32<true>(bufA, sv, mav, gv, red, ldsbase);
    LDS_FENCE(); reduce32(2); LDS_FENCE();
    proc32<true>(bufB, sv, mav, gv, red, ldsbase);
    LDS_FENCE(); reduce32(3);
}

} // namespace

extern "C" void kernel_launch(void* const* d_in, const int* in_sizes, int n_in,
                              void* d_out, int out_size, void* d_ws, size_t ws_size,
                              hipStream_t stream)
{
    (void)in_sizes; (void)n_in; (void)out_size; (void)d_ws; (void)ws_size;
    const float* ex   = (const float*)d_in[0];
    const float* gain = (const float*)d_in[1];
    const float* a    = (const float*)d_in[2];
    float* out        = (float*)d_out;

    dim3 grid(2048);   // 16 batches x 2048 half-blocks / 16 per wave -> 8 waves/CU
    dim3 block(64);
    hipLaunchKernelGGL(lpc_ola_kernel, grid, block, 0, stream, ex, gain, a, out);
}

// Round 4
// 89.551 us; speedup vs baseline: 1.3345x; 1.0184x over previous
//
#include <hip/hip_runtime.h>

namespace {

typedef float v2f __attribute__((ext_vector_type(2)));

constexpr int T_LEN = 262144;   // samples per batch
constexpr int NF    = 1024;     // frames per batch

// Sum x across each quad of lanes (4 overlap slots) with two DPP quad_perm
// adds: xor1 = perm[1,0,3,2] = 0xB1, xor2 = perm[2,3,0,1] = 0x4E. No LDS.
__device__ __forceinline__ float qsum(float x) {
    x += __int_as_float(__builtin_amdgcn_update_dpp(
             0, __float_as_int(x), 0xB1, 0xF, 0xF, true));
    x += __int_as_float(__builtin_amdgcn_update_dpp(
             0, __float_as_int(x), 0x4E, 0xF, 0xF, true));
    return x;
}

template <bool CK>
__device__ __forceinline__ void ld4(const float* __restrict__ exb, int xi,
                                    float4 (&buf)[4]) {
    #pragma unroll
    for (int q = 0; q < 4; ++q) {
        const int idx = xi + q * 4;
        if (CK) {   // only wave 0 of each batch can touch idx<0; upper bound proven
            float4 v = make_float4(0.f, 0.f, 0.f, 0.f);
            if (idx >= 0) v = *(const float4*)(exb + idx);
            buf[q] = v;
        } else {
            buf[q] = *(const float4*)(exb + idx);
        }
    }
}

// 4 samples of order-22 IIR (transposed DF-II), state packed (s[j], s[j+11])
// so the delay-line shift maps onto v_pk_fma_f32. 13 VALU inst / sample.
__device__ __forceinline__ void iir4(const float4& x4, v2f (&sv)[11],
                                     const v2f (&mav)[11], float gv,
                                     float (&yo)[4]) {
    const float xv[4] = {x4.x, x4.y, x4.z, x4.w};
    #pragma unroll
    for (int u = 0; u < 4; ++u) {
        float y   = fmaf(gv, xv[u], sv[0].x);
        float s11 = sv[0].y;
        v2f yy = (v2f){y, y};
        #pragma unroll
        for (int j = 0; j < 10; ++j)
            sv[j] = __builtin_elementwise_fma(mav[j], yy, sv[j + 1]);
        sv[10].x = fmaf(mav[10].x, y, s11);
        sv[10].y = mav[10].y * y;
        yo[u] = y;
    }
}

__device__ __forceinline__ void proc16w(const float4 (&buf)[4], v2f (&sv)[11],
                                        const v2f (&mav)[11], float gv) {
    float yd[4];
    #pragma unroll
    for (int q = 0; q < 4; ++q) iir4(buf[q], sv, mav, gv, yd);
}

// 16 output samples: IIR + per-lane hann weight (one v_cos each) + quad DPP
// reduction + predicated float4 store (lane kk owns quarter kk of the block).
template <bool EDGE>
__device__ __forceinline__ void proc16o(const float4 (&buf)[4], v2f (&sv)[11],
                                        const v2f (&mav)[11], float gv,
                                        float& rev, float cA, float cB,
                                        bool st, float* __restrict__ outp) {
    #pragma unroll
    for (int q = 0; q < 4; ++q) {
        float y[4];
        iir4(buf[q], sv, mav, gv, y);
        float o[4];
        #pragma unroll
        for (int u = 0; u < 4; ++u) {
            float c = __builtin_amdgcn_cosf(rev);   // cos(2*pi*rev), rev in [0,1)
            rev += (1.0f / 1024.0f);
            float wl = fmaf(cA, c, cB);             // scaled hann * validity mask
            float v  = wl * y[u];
            if (EDGE) {
                o[u] = qsum(v) * __builtin_amdgcn_rcpf(qsum(wl));
            } else {
                o[u] = qsum(v);   // interior: wsum == 2, 0.25 scale folded in cA/cB
            }
        }
        if (st) *(float4*)(outp + q * 4) = make_float4(o[0], o[1], o[2], o[3]);
    }
}

// Per batch: 2048 output blocks of 128 samples (i = 3..2050; out base i*128-384
// tiles [0, 262144) exactly). Quad slot kk reads frame f = (i>>1)-kk starting
// 128 warm samples (zero-state truncation, validated absmax ~0.008) before its
// 128 output samples. No LDS, no barriers, single-pass.
__global__ __launch_bounds__(64, 2)
void lpc_ola_kernel(const float* __restrict__ ex,
                    const float* __restrict__ gain,
                    const float* __restrict__ a,
                    float* __restrict__ out)
{
    const int lane = threadIdx.x;
    const int w    = blockIdx.x;
    const int wloc = w & 127;
    const bool chk  = (wloc == 0);
    const bool edge = (wloc == 0) | (wloc == 127);

    const int kk = lane & 3;          // overlap slot (within quad)
    const int jl = lane >> 2;         // task-in-wave
    const int tau = w * 16 + jl;
    const int b  = tau >> 11;
    const int i  = (tau & 2047) + 3;
    const int fi = i >> 1;
    const int f  = fi - kk;
    const bool fv = (unsigned)f < (unsigned)NF;
    const int fc = fv ? f : 0;
    const float mval = fv ? 1.f : 0.f;
    const float gv   = fv ? gain[b * NF + fc] : 0.f;  // y=0 for invalid slots

    v2f mav[11];
    {
        const float2* ap = (const float2*)(a + (size_t)(b * NF + fc) * 22);
        float man[22];
        #pragma unroll
        for (int j = 0; j < 11; ++j) {
            float2 t = ap[j];
            man[2 * j] = -t.x; man[2 * j + 1] = -t.y;
        }
        #pragma unroll
        for (int j = 0; j < 11; ++j) mav[j] = (v2f){man[j], man[j + 11]};
    }
    v2f sv[11];
    #pragma unroll
    for (int j = 0; j < 11; ++j) sv[j] = (v2f){0.f, 0.f};

    const float* exb = ex + (size_t)b * T_LEN;
    int xi = i * 128 - 512;                         // first warm sample (kk-indep)
    const int m0k = kk * 256 + ((i & 1) << 7);      // frame-local idx of out sample 0
    float rev = (float)m0k * (1.0f / 1024.0f);
    const float scale = edge ? 0.5f : 0.25f;
    const float cA = -scale * mval, cB = scale * mval;
    float* outp0 = out + (size_t)b * T_LEN + (i * 128 - 384);

    float4 A[4], B[4];
    if (chk) { ld4<true >(exb, xi, A); xi += 16; ld4<true >(exb, xi, B); xi += 16; }
    else     { ld4<false>(exb, xi, A); xi += 16; ld4<false>(exb, xi, B); xi += 16; }

    // ---- warm: 128 samples = 8 sub-blocks, ping-pong refill-after-use ----
    #pragma unroll 1
    for (int it = 0; it < 4; ++it) {
        proc16w(A, sv, mav, gv);
        if (chk) ld4<true>(exb, xi, A); else ld4<false>(exb, xi, A);
        xi += 16;
        proc16w(B, sv, mav, gv);
        if (chk) ld4<true>(exb, xi, B); else ld4<false>(exb, xi, B);
        xi += 16;
    }
    // A = out sub-block 0, B = out sub-block 1 (loaded by warm loop's tail)

    // ---- out: 128 samples = 8 sub-blocks ----
    if (!edge) {
        #pragma unroll 1
        for (int it = 0; it < 4; ++it) {
            const int sb = 2 * it;
            proc16o<false>(A, sv, mav, gv, rev, cA, cB,
                           kk == (sb >> 1), outp0 + sb * 16);
            if (it < 3) { ld4<false>(exb, xi, A); xi += 16; }
            proc16o<false>(B, sv, mav, gv, rev, cA, cB,
                           kk == ((sb + 1) >> 1), outp0 + (sb + 1) * 16);
            if (it < 3) { ld4<false>(exb, xi, B); xi += 16; }
        }
    } else {
        #pragma unroll 1
        for (int it = 0; it < 4; ++it) {
            const int sb = 2 * it;
            proc16o<true>(A, sv, mav, gv, rev, cA, cB,
                          kk == (sb >> 1), outp0 + sb * 16);
            if (it < 3) { ld4<false>(exb, xi, A); xi += 16; }
            proc16o<true>(B, sv, mav, gv, rev, cA, cB,
                          kk == ((sb + 1) >> 1), outp0 + (sb + 1) * 16);
            if (it < 3) { ld4<false>(exb, xi, B); xi += 16; }
        }
    }
}

} // namespace

extern "C" void kernel_launch(void* const* d_in, const int* in_sizes, int n_in,
                              void* d_out, int out_size, void* d_ws, size_t ws_size,
                              hipStream_t stream)
{
    (void)in_sizes; (void)n_in; (void)out_size; (void)d_ws; (void)ws_size;
    const float* ex   = (const float*)d_in[0];
    const float* gain = (const float*)d_in[1];
    const float* a    = (const float*)d_in[2];
    float* out        = (float*)d_out;

    dim3 grid(2048);   // 16 batches x 2048 blocks / 16 tasks per wave
    dim3 block(64);
    hipLaunchKernelGGL(lpc_ola_kernel, grid, block, 0, stream, ex, gain, a, out);
}